// Round 7
// baseline (573.529 us; speedup 1.0000x reference)
//
#include <hip/hip_runtime.h>
#include <math.h>

// CRITICAL: no FMA contraction — bit-replicating numpy's SSE float32 einsum.
#pragma clang fp contract(off)

#define T_TOKENS 16384
#define HDIM 2048
#define NEXP 64
#define TOPK 6
#define SEQ 4096
#define TPB 32          // tokens per block
#define NTHR 128        // 2 waves
#define LGS 65          // padded stride for logits/probs scratch

// numpy einsum contig_two micro-step (SSE, 4 lanes, no FMA), proven bit-exact
// in round 3: per 16-k block, SSE lane l chains k = 4j + l, j applied 3..0:
//   v = a0*b0 + (a1*b1 + (a2*b2 + (a3*b3 + v)))
__device__ __forceinline__ void np_upd(const float4& w0, const float4& w1,
                                       const float4& w2, const float4& w3,
                                       const float4& x0, const float4& x1,
                                       const float4& x2, const float4& x3,
                                       float acc[4])
{
    acc[0] = w0.x*x0.x + (w1.x*x1.x + (w2.x*x2.x + (w3.x*x3.x + acc[0])));
    acc[1] = w0.y*x0.y + (w1.y*x1.y + (w2.y*x2.y + (w3.y*x3.y + acc[1])));
    acc[2] = w0.z*x0.z + (w1.z*x1.z + (w2.z*x2.z + (w3.z*x3.z + acc[2])));
    acc[3] = w0.w*x0.w + (w1.w*x1.w + (w2.w*x2.w + (w3.w*x3.w + acc[3])));
}

// Thread layout (128 thr): le = tid&15 -> experts {le, le+16, le+32, le+48}
//   tg = tid>>4 (0..7) -> tokens tg*4 .. tg*4+3
// NO LDS, NO barriers in the K-loop: W (512 KB, L2-resident) and x both read
// directly from global with float4 streams.
__global__ __launch_bounds__(NTHR, 2) void moe_gate_main(
    const float* __restrict__ x, const float* __restrict__ wgt,
    float* __restrict__ out, float* __restrict__ gacc)
{
    __shared__ float lg[TPB * LGS];       // 8320 B
    __shared__ float probs[TPB * LGS];    // 8320 B
    __shared__ float psum[2 * NEXP];      //  512 B
    __shared__ int   cnt[NEXP];           //  256 B

    const int tid = threadIdx.x;
    const int bid = blockIdx.x;
    const int tb  = bid * TPB;
    const int b   = tb >> 12;             // /4096

    const int le = tid & 15;
    const int tg = tid >> 4;              // 0..7
    const int t0 = tg * 4;

    const float* wp0 = wgt + (size_t)(le     ) * HDIM;
    const float* wp1 = wgt + (size_t)(le + 16) * HDIM;
    const float* wp2 = wgt + (size_t)(le + 32) * HDIM;
    const float* wp3 = wgt + (size_t)(le + 48) * HDIM;
    const float* xp0 = x + (size_t)(tb + t0    ) * HDIM;
    const float* xp1 = x + (size_t)(tb + t0 + 1) * HDIM;
    const float* xp2 = x + (size_t)(tb + t0 + 2) * HDIM;
    const float* xp3 = x + (size_t)(tb + t0 + 3) * HDIM;

    float acc[4][4][4];                   // [expert je][token tt][sse lane]
    #pragma unroll
    for (int je = 0; je < 4; ++je)
        #pragma unroll
        for (int tt = 0; tt < 4; ++tt)
            #pragma unroll
            for (int l = 0; l < 4; ++l) acc[je][tt][l] = 0.f;

    for (int kb = 0; kb < HDIM; kb += 16) {
        // x fragments: 16 float4 (4 tokens x 16 k), contiguous per token
        float4 xv[4][4];
        #pragma unroll
        for (int j = 0; j < 4; ++j) {
            xv[0][j] = *reinterpret_cast<const float4*>(xp0 + kb + 4 * j);
            xv[1][j] = *reinterpret_cast<const float4*>(xp1 + kb + 4 * j);
            xv[2][j] = *reinterpret_cast<const float4*>(xp2 + kb + 4 * j);
            xv[3][j] = *reinterpret_cast<const float4*>(xp3 + kb + 4 * j);
        }
        // per expert row: 4 float4 of W (L2-resident), then 4 tokens' chains
        {
            float4 w0 = *reinterpret_cast<const float4*>(wp0 + kb);
            float4 w1 = *reinterpret_cast<const float4*>(wp0 + kb + 4);
            float4 w2 = *reinterpret_cast<const float4*>(wp0 + kb + 8);
            float4 w3 = *reinterpret_cast<const float4*>(wp0 + kb + 12);
            #pragma unroll
            for (int tt = 0; tt < 4; ++tt)
                np_upd(w0, w1, w2, w3, xv[tt][0], xv[tt][1], xv[tt][2], xv[tt][3], acc[0][tt]);
        }
        {
            float4 w0 = *reinterpret_cast<const float4*>(wp1 + kb);
            float4 w1 = *reinterpret_cast<const float4*>(wp1 + kb + 4);
            float4 w2 = *reinterpret_cast<const float4*>(wp1 + kb + 8);
            float4 w3 = *reinterpret_cast<const float4*>(wp1 + kb + 12);
            #pragma unroll
            for (int tt = 0; tt < 4; ++tt)
                np_upd(w0, w1, w2, w3, xv[tt][0], xv[tt][1], xv[tt][2], xv[tt][3], acc[1][tt]);
        }
        {
            float4 w0 = *reinterpret_cast<const float4*>(wp2 + kb);
            float4 w1 = *reinterpret_cast<const float4*>(wp2 + kb + 4);
            float4 w2 = *reinterpret_cast<const float4*>(wp2 + kb + 8);
            float4 w3 = *reinterpret_cast<const float4*>(wp2 + kb + 12);
            #pragma unroll
            for (int tt = 0; tt < 4; ++tt)
                np_upd(w0, w1, w2, w3, xv[tt][0], xv[tt][1], xv[tt][2], xv[tt][3], acc[2][tt]);
        }
        {
            float4 w0 = *reinterpret_cast<const float4*>(wp3 + kb);
            float4 w1 = *reinterpret_cast<const float4*>(wp3 + kb + 4);
            float4 w2 = *reinterpret_cast<const float4*>(wp3 + kb + 8);
            float4 w3 = *reinterpret_cast<const float4*>(wp3 + kb + 12);
            #pragma unroll
            for (int tt = 0; tt < 4; ++tt)
                np_upd(w0, w1, w2, w3, xv[tt][0], xv[tt][1], xv[tt][2], xv[tt][3], acc[3][tt]);
        }
    }

    // ---- logits: hadd exactly like npyv_sum_f32: (v0+v1)+(v2+v3)
    #pragma unroll
    for (int je = 0; je < 4; ++je)
        #pragma unroll
        for (int tt = 0; tt < 4; ++tt) {
            float v = (acc[je][tt][0] + acc[je][tt][1]) + (acc[je][tt][2] + acc[je][tt][3]);
            lg[(t0 + tt) * LGS + le + 16 * je] = v;
        }
    if (tid < NEXP) cnt[tid] = 0;
    __syncthreads();

    // ---- softmax per token (threads 0..31), fp32, numpy pairwise sum
    if (tid < TPB) {
        const int t = tid;
        float mx = lg[t * LGS];
        for (int e = 1; e < NEXP; ++e) { float v = lg[t * LGS + e]; if (v > mx) mx = v; }
        for (int e = 0; e < NEXP; ++e)
            probs[t * LGS + e] = expf(lg[t * LGS + e] - mx);
        float r[8];
        #pragma unroll
        for (int j = 0; j < 8; ++j) r[j] = probs[t * LGS + j];
        for (int i = 8; i < 64; i += 8)
            #pragma unroll
            for (int j = 0; j < 8; ++j) r[j] += probs[t * LGS + i + j];
        float S = ((r[0] + r[1]) + (r[2] + r[3])) + ((r[4] + r[5]) + (r[6] + r[7]));
        for (int e = 0; e < NEXP; ++e) probs[t * LGS + e] = probs[t * LGS + e] / S;
    }
    __syncthreads();

    // ---- partial per-expert prob sums (aux loss), all 128 threads
    {
        const int e = tid & 63, q = tid >> 6;
        float s = 0.f;
        for (int t = q * 16; t < q * 16 + 16; ++t) s += probs[t * LGS + e];
        psum[q * 64 + e] = s;
    }
    __syncthreads();

    if (tid < TPB) {
        // ---- top-6 on probs, strict > ascending scan (tie -> lowest index)
        const int t = tid;
        const int gt = tb + t;
        float pv[TOPK]; int pi[TOPK];
        for (int r = 0; r < TOPK; ++r) {
            float bv = -1.f; int be = 0;
            for (int e = 0; e < NEXP; ++e) {
                float v = probs[t * LGS + e];
                if (v > bv) { bv = v; be = e; }
            }
            probs[t * LGS + be] = -1.f;
            pv[r] = bv; pi[r] = be;
            atomicAdd(&cnt[be], 1);
        }
        float wsum = pv[0];
        #pragma unroll
        for (int r = 1; r < TOPK; ++r) wsum += pv[r];
        wsum += 1e-20f;
        #pragma unroll
        for (int r = 0; r < TOPK; ++r) {
            out[(size_t)gt * TOPK + r] = (float)pi[r];
            out[(size_t)T_TOKENS * TOPK + (size_t)gt * TOPK + r] = pv[r] / wsum;
        }
    } else if (tid >= 64 && tid < 128) {
        const int e = tid - 64;
        atomicAdd(&gacc[b * 64 + e], psum[e] + psum[64 + e]);
    }
    __syncthreads();
    if (tid < NEXP) {
        atomicAdd(&gacc[256 + b * 64 + tid], (float)cnt[tid]);
    }
}

// Finalize: aux = ALPHA * mean_b( sum_e (cnt*E/(S*K)) * (ssum/S) )
__global__ __launch_bounds__(256) void moe_gate_aux(
    const float* __restrict__ gacc, float* __restrict__ out)
{
    __shared__ float red[4];
    const int tid = threadIdx.x;
    float v = gacc[256 + tid] * gacc[tid];
    #pragma unroll
    for (int o = 32; o > 0; o >>= 1) v += __shfl_down(v, o, 64);
    if ((tid & 63) == 0) red[tid >> 6] = v;
    __syncthreads();
    if (tid == 0) {
        float tot = red[0] + red[1] + red[2] + red[3];
        const float scale = (64.0f / (4096.0f * 6.0f)) / 4096.0f;
        out[2 * T_TOKENS * TOPK] = 1e-3f * (tot * scale) * 0.25f;
    }
}

extern "C" void kernel_launch(void* const* d_in, const int* in_sizes, int n_in,
                              void* d_out, int out_size, void* d_ws, size_t ws_size,
                              hipStream_t stream) {
    const float* x   = (const float*)d_in[0];
    const float* wgt = (const float*)d_in[1];
    float* out  = (float*)d_out;
    float* gacc = (float*)d_ws;

    hipMemsetAsync(d_ws, 0, 512 * sizeof(float), stream);
    moe_gate_main<<<T_TOKENS / TPB, NTHR, 0, stream>>>(x, wgt, out, gacc);
    moe_gate_aux<<<1, 256, 0, stream>>>(gacc, out);
}